// Round 1
// baseline (49193.091 us; speedup 1.0000x reference)
//
#include <hip/hip_runtime.h>
#include <math.h>

#define NB 256       // batch
#define LAT 128
#define UPS 64
#define H 512
#define V 25
#define TS 500       // time steps
#define H3 1536
#define EGI_STRIDE 32

// ---------------- init kernels (run once per launch) ----------------

// E_giT[n][v] = b_ih[n] + embed[v,:] . W_ih[n,:]   (n < 3H, v < V), stored transposed stride 32
__global__ void k_init_egi(const float* __restrict__ embed, const float* __restrict__ W_ih,
                           const float* __restrict__ b_ih, float* __restrict__ EgiT) {
    int idx = blockIdx.x * 256 + threadIdx.x;
    if (idx >= V * H3) return;
    int v = idx % V, n = idx / V;
    const float* e = embed + (size_t)v * H;
    const float* w = W_ih + (size_t)n * H;
    float acc = b_ih[n];
    for (int k = 0; k < H; k++) acc += e[k] * w[k];
    EgiT[(size_t)n * EGI_STRIDE + v] = acc;
}

// hT0[j][b] = b_hid[j] + latent[b,:] . W_hid[j,:] ; ids = SOS
__global__ void k_init_h0(const float* __restrict__ latent, const float* __restrict__ W_hid,
                          const float* __restrict__ b_hid, float* __restrict__ hT0,
                          int* __restrict__ ids) {
    int j = blockIdx.x;
    int b = threadIdx.x;
    const float* l = latent + (size_t)b * LAT;
    const float* w = W_hid + (size_t)j * LAT;
    float acc = b_hid[j];
    for (int k = 0; k < LAT; k++) acc += l[k] * w[k];
    hT0[(size_t)j * NB + b] = acc;
    if (blockIdx.x == 0) ids[b] = 0;  // SOS
}

// Wfold[j][u] = sum_k W_cat[j][512+k] * W_mem[k][u]
__global__ void k_init_fold(const float* __restrict__ W_cat, const float* __restrict__ W_mem,
                            float* __restrict__ Wfold) {
    int idx = blockIdx.x * 256 + threadIdx.x;
    if (idx >= H * UPS) return;
    int u = idx & 63, j = idx >> 6;
    float acc = 0.f;
    for (int k = 0; k < H; k++)
        acc += W_cat[(size_t)j * 1024 + 512 + k] * W_mem[(size_t)k * UPS + u];
    Wfold[(size_t)j * UPS + u] = acc;
}

// bcat2[j] = b_cat[j] + sum_k W_cat[j][512+k] * b_mem[k]
__global__ void k_init_bcat(const float* __restrict__ W_cat, const float* __restrict__ b_mem,
                            const float* __restrict__ b_cat, float* __restrict__ bcat2) {
    int j = blockIdx.x * 256 + threadIdx.x;
    if (j >= H) return;
    float acc = b_cat[j];
    for (int k = 0; k < H; k++) acc += W_cat[(size_t)j * 1024 + 512 + k] * b_mem[k];
    bcat2[j] = acc;
}

// ---------------- per-step kernels ----------------

// P1: GRU cell.  grid 256 blocks (4 b-quarters x 64 j-groups), 256 threads.
// wave w handles 2 j's; lane = b within quarter. All weight loads wave-uniform.
__global__ __launch_bounds__(256) void k_p1(const float* __restrict__ hc, float* __restrict__ hn,
                                            const float* __restrict__ EgiT,
                                            const float* __restrict__ W_hh,
                                            const float* __restrict__ b_hh,
                                            const int* __restrict__ ids) {
    const int tid = threadIdx.x;
    const int lane = tid & 63, w = tid >> 6;
    const int bq = blockIdx.x & 3, jb = blockIdx.x >> 2;
    const int b = bq * 64 + lane;
    const int j0 = jb * 8 + w * 2;
    const int id = ids[b];
    float acc[2][3] = {{0.f, 0.f, 0.f}, {0.f, 0.f, 0.f}};
    for (int k4 = 0; k4 < H / 4; k4++) {
        const int k = k4 * 4;
        const float h0v = hc[(size_t)(k + 0) * NB + b];
        const float h1v = hc[(size_t)(k + 1) * NB + b];
        const float h2v = hc[(size_t)(k + 2) * NB + b];
        const float h3v = hc[(size_t)(k + 3) * NB + b];
#pragma unroll
        for (int jj = 0; jj < 2; jj++) {
#pragma unroll
            for (int g = 0; g < 3; g++) {
                const float4 wv = *(const float4*)(W_hh + ((size_t)(j0 + jj) + (size_t)g * H) * H + k);
                acc[jj][g] += h0v * wv.x + h1v * wv.y + h2v * wv.z + h3v * wv.w;
            }
        }
    }
#pragma unroll
    for (int jj = 0; jj < 2; jj++) {
        const int j = j0 + jj;
        const float gir = EgiT[(size_t)j * EGI_STRIDE + id];
        const float giz = EgiT[(size_t)(j + H) * EGI_STRIDE + id];
        const float gin = EgiT[(size_t)(j + 2 * H) * EGI_STRIDE + id];
        const float hr = acc[jj][0] + b_hh[j];
        const float hz = acc[jj][1] + b_hh[j + H];
        const float hnn = acc[jj][2] + b_hh[j + 2 * H];
        const float r = 1.f / (1.f + expf(-(gir + hr)));
        const float z = 1.f / (1.f + expf(-(giz + hz)));
        const float n = tanhf(gin + r * hnn);
        const float hold = hc[(size_t)j * NB + b];
        hn[(size_t)j * NB + b] = (1.f - z) * n + z * hold;
    }
}

// P2: attention in up-space. One block per batch row b.
__global__ __launch_bounds__(256) void k_p2(const float* __restrict__ hn,
                                            const float* __restrict__ W_mem,
                                            const float* __restrict__ up,
                                            float* __restrict__ uctxT) {
    const int b = blockIdx.x;
    const int tid = threadIdx.x, lane = tid & 63, w = tid >> 6;
    __shared__ __align__(16) float hp[UPS];
    __shared__ float part[4][UPS];
    __shared__ __align__(16) float sc[512];
    __shared__ float red[4], red2[4];

    // hproj[u] = sum_k h_new[k] * W_mem[k][u]
    {
        float acc = 0.f;
        for (int k = w * 128; k < w * 128 + 128; k++)
            acc += hn[(size_t)k * NB + b] * W_mem[(size_t)k * UPS + lane];
        part[w][lane] = acc;
    }
    __syncthreads();
    if (w == 0) hp[lane] = part[0][lane] + part[1][lane] + part[2][lane] + part[3][lane];
    __syncthreads();

    // scores + max
    float lm = -1e30f;
    const float4* hp4 = (const float4*)hp;
    for (int t = tid; t < TS; t += 256) {
        const float4* ur = (const float4*)(up + ((size_t)b * TS + t) * UPS);
        float s = 0.f;
#pragma unroll
        for (int i = 0; i < UPS / 4; i++) {
            const float4 a = ur[i];
            const float4 hh = hp4[i];
            s += a.x * hh.x + a.y * hh.y + a.z * hh.z + a.w * hh.w;
        }
        sc[t] = s;
        lm = fmaxf(lm, s);
    }
    for (int off = 32; off; off >>= 1) lm = fmaxf(lm, __shfl_xor(lm, off));
    if (lane == 0) red[w] = lm;
    __syncthreads();
    const float m = fmaxf(fmaxf(red[0], red[1]), fmaxf(red[2], red[3]));

    // exp + sum  (each thread owns the same t's it wrote)
    float ls = 0.f;
    for (int t = tid; t < TS; t += 256) {
        const float e = expf(sc[t] - m);
        sc[t] = e;
        ls += e;
    }
    __syncthreads();  // sc[] now finalized for all threads
    for (int off = 32; off; off >>= 1) ls += __shfl_xor(ls, off);
    if (lane == 0) red2[w] = ls;
    __syncthreads();
    const float S = red2[0] + red2[1] + red2[2] + red2[3];

    // uctx[u] = sum_t w_t * up[b,t,u] / S   (wave w takes t = w mod 4)
    {
        float acc = 0.f;
        for (int t = w; t < TS; t += 4)
            acc += sc[t] * up[((size_t)b * TS + t) * UPS + lane];
        part[w][lane] = acc;
    }
    __syncthreads();
    if (w == 0)
        uctxT[(size_t)lane * NB + b] =
            (part[0][lane] + part[1][lane] + part[2][lane] + part[3][lane]) / S;
}

// P3: concat = tanh(h_new @ Wc1^T + uctx @ Wfold^T + bcat2). Same layout as P1.
__global__ __launch_bounds__(256) void k_p3(const float* __restrict__ hn,
                                            const float* __restrict__ uctxT,
                                            const float* __restrict__ W_cat,
                                            const float* __restrict__ Wfold,
                                            const float* __restrict__ bcat2,
                                            float* __restrict__ concatT) {
    const int tid = threadIdx.x, lane = tid & 63, w = tid >> 6;
    const int bq = blockIdx.x & 3, jb = blockIdx.x >> 2;
    const int b = bq * 64 + lane;
    const int j0 = jb * 8 + w * 2;
    float acc[2] = {0.f, 0.f};
    for (int k4 = 0; k4 < H / 4; k4++) {
        const int k = k4 * 4;
        const float h0v = hn[(size_t)(k + 0) * NB + b];
        const float h1v = hn[(size_t)(k + 1) * NB + b];
        const float h2v = hn[(size_t)(k + 2) * NB + b];
        const float h3v = hn[(size_t)(k + 3) * NB + b];
#pragma unroll
        for (int jj = 0; jj < 2; jj++) {
            const float4 wv = *(const float4*)(W_cat + (size_t)(j0 + jj) * 1024 + k);
            acc[jj] += h0v * wv.x + h1v * wv.y + h2v * wv.z + h3v * wv.w;
        }
    }
    for (int u4 = 0; u4 < UPS / 4; u4++) {
        const int u = u4 * 4;
        const float c0 = uctxT[(size_t)(u + 0) * NB + b];
        const float c1 = uctxT[(size_t)(u + 1) * NB + b];
        const float c2 = uctxT[(size_t)(u + 2) * NB + b];
        const float c3 = uctxT[(size_t)(u + 3) * NB + b];
#pragma unroll
        for (int jj = 0; jj < 2; jj++) {
            const float4 wv = *(const float4*)(Wfold + (size_t)(j0 + jj) * UPS + u);
            acc[jj] += c0 * wv.x + c1 * wv.y + c2 * wv.z + c3 * wv.w;
        }
    }
#pragma unroll
    for (int jj = 0; jj < 2; jj++) {
        const int j = j0 + jj;
        concatT[(size_t)j * NB + b] = tanhf(acc[jj] + bcat2[j]);
    }
}

// P4: logits + greedy argmax + output write. One block per b, 256 threads (k split by wave).
__global__ __launch_bounds__(256) void k_p4(const float* __restrict__ concatT,
                                            const float* __restrict__ W_out,
                                            const float* __restrict__ b_out,
                                            float* __restrict__ out, int* __restrict__ ids,
                                            int t) {
    const int b = blockIdx.x, tid = threadIdx.x, lane = tid & 63, w = tid >> 6;
    __shared__ float part[4][V];
    __shared__ float lg[V];
    if (lane < V) {
        float acc = 0.f;
        for (int k4 = w * 32; k4 < w * 32 + 32; k4++) {
            const int k = k4 * 4;
            const float c0 = concatT[(size_t)(k + 0) * NB + b];
            const float c1 = concatT[(size_t)(k + 1) * NB + b];
            const float c2 = concatT[(size_t)(k + 2) * NB + b];
            const float c3 = concatT[(size_t)(k + 3) * NB + b];
            const float4 wv = *(const float4*)(W_out + (size_t)lane * H + k);
            acc += c0 * wv.x + c1 * wv.y + c2 * wv.z + c3 * wv.w;
        }
        part[w][lane] = acc;
    }
    __syncthreads();
    if (tid < V) {
        const float l = part[0][tid] + part[1][tid] + part[2][tid] + part[3][tid] + b_out[tid];
        lg[tid] = l;
        out[(size_t)b * V * TS + (size_t)tid * TS + t] = l;
    }
    __syncthreads();
    if (tid == 0) {
        float best = lg[0];
        int bi = 0;
        for (int v = 1; v < V; v++)
            if (lg[v] > best) { best = lg[v]; bi = v; }  // first-max, matches jnp.argmax
        ids[b] = bi;
    }
}

// ---------------- launcher ----------------

extern "C" void kernel_launch(void* const* d_in, const int* in_sizes, int n_in,
                              void* d_out, int out_size, void* d_ws, size_t ws_size,
                              hipStream_t stream) {
    const float* latent = (const float*)d_in[0];
    const float* up     = (const float*)d_in[1];
    const float* embed  = (const float*)d_in[2];
    const float* W_hid  = (const float*)d_in[3];
    const float* b_hid  = (const float*)d_in[4];
    const float* W_ih   = (const float*)d_in[5];
    const float* b_ih   = (const float*)d_in[6];
    const float* W_hh   = (const float*)d_in[7];
    const float* b_hh   = (const float*)d_in[8];
    const float* W_mem  = (const float*)d_in[9];
    const float* b_mem  = (const float*)d_in[10];
    const float* W_cat  = (const float*)d_in[11];
    const float* b_cat  = (const float*)d_in[12];
    const float* W_out  = (const float*)d_in[13];
    const float* b_out  = (const float*)d_in[14];
    float* out = (float*)d_out;

    float* ws = (float*)d_ws;
    float* hT      = ws;                        // [2][H][NB]
    float* uctxT   = hT + 2 * H * NB;           // [UPS][NB]
    float* concatT = uctxT + UPS * NB;          // [H][NB]
    float* EgiT    = concatT + H * NB;          // [H3][32]
    float* Wfold   = EgiT + H3 * EGI_STRIDE;    // [H][UPS]
    float* bcat2   = Wfold + H * UPS;           // [H]
    int*   ids     = (int*)(bcat2 + H);         // [NB]

    k_init_egi<<<(V * H3 + 255) / 256, 256, 0, stream>>>(embed, W_ih, b_ih, EgiT);
    k_init_h0<<<H, NB, 0, stream>>>(latent, W_hid, b_hid, hT, ids);
    k_init_fold<<<(H * UPS + 255) / 256, 256, 0, stream>>>(W_cat, W_mem, Wfold);
    k_init_bcat<<<(H + 255) / 256, 256, 0, stream>>>(W_cat, b_mem, b_cat, bcat2);

    for (int t = 0; t < TS; t++) {
        float* hc = hT + (size_t)(t & 1) * H * NB;
        float* hn = hT + (size_t)((t + 1) & 1) * H * NB;
        k_p1<<<256, 256, 0, stream>>>(hc, hn, EgiT, W_hh, b_hh, ids);
        k_p2<<<NB, 256, 0, stream>>>(hn, W_mem, up, uctxT);
        k_p3<<<256, 256, 0, stream>>>(hn, uctxT, W_cat, Wfold, bcat2, concatT);
        k_p4<<<NB, 256, 0, stream>>>(concatT, W_out, b_out, out, ids, t);
    }
}